// Round 1
// baseline (240.553 us; speedup 1.0000x reference)
//
#include <hip/hip_runtime.h>
#include <stdint.h>

// ---- Paillier constants (P=59, Q=61) ----
static constexpr uint32_t PP  = 59, QQ = 61;
static constexpr uint32_t Nn  = PP * QQ;        // 3599
static constexpr uint32_t P2  = PP * PP;        // 3481
static constexpr uint32_t Q2  = QQ * QQ;        // 3721
static constexpr uint32_t LAM = 1740;           // lcm(58,60)

constexpr uint32_t cinv(uint32_t a, uint32_t m) {   // brute-force modular inverse
    for (uint32_t x = 1; x < m; ++x) if ((uint64_t)a * x % m == 1u) return x;
    return 0u;
}
static constexpr uint32_t MU  = cinv(LAM % Nn, Nn);   // 1119 = lambda^-1 mod n
static constexpr uint32_t IQP = cinv(P2 % Q2, Q2);    // (p^2)^-1 mod q^2
static constexpr uint32_t GAM = cinv(PP % QQ, QQ);    // p^-1 mod q = 30
static constexpr uint32_t CPP = (cinv(QQ % PP, PP) * (MU % PP)) % PP;  // q^-1*mu mod p
static constexpr uint32_t CQQ = (cinv(PP % QQ, QQ) * (MU % QQ)) % QQ;  // p^-1*mu mod q

static constexpr int TPN = 3484;                // Tp u32 count (3481 padded to /4)
static constexpr int TQN = 3724;                // Tq u32 count (3721 padded to /4)
static constexpr int TT  = TPN + TQN;           // 7208 u32 = 28832 B
static constexpr size_t WS_NEED = (size_t)TT * 4;

// ---- full-rate 24-bit multiplies (operands provably < 2^24) ----
__device__ __forceinline__ uint32_t mul24lo(uint32_t a, uint32_t b) {
    uint32_t r;
    asm("v_mul_u32_u24 %0, %1, %2" : "=v"(r) : "v"(a), "v"(b));
    return r;
}
__device__ __forceinline__ uint32_t mul24hi(uint32_t a, uint32_t b) {
    uint32_t r;                                   // (u24(a)*u24(b)) >> 32
    asm("v_mul_hi_u32_u24 %0, %1, %2" : "=v"(r) : "v"(a), "v"(b));
    return r;
}
__device__ __forceinline__ uint32_t mad24_59(uint32_t a, uint32_t c) {
    uint32_t r;                                   // a*59 + c, all < 2^24
    asm("v_mad_u32_u24 %0, %1, 59, %2" : "=v"(r) : "v"(a), "v"(c));
    return r;
}

// x < 2^24, D ~ 3500: x mod D via 2^32 magic (no shift needed).
// M = floor(2^32/D) < 2^24; q = (x*M)>>32 underestimates floor(x/D) by
// < x/2^32 < 2^-8, so q ∈ {Q-1, Q}; one min-correction suffices. Exact.
template<uint32_t D>
__device__ __forceinline__ uint32_t mod24(uint32_t x) {
    constexpr uint32_t M = (uint32_t)((1ull << 32) / D);
    uint32_t q = mul24hi(x, M);
    uint32_t r = x - mul24lo(q, D);           // ∈ [0, 2D)
    return min(r, r - D);                     // unsigned wrap trick
}

// ---- table construction (exact; runs once over 3724 threads) ----
template<uint32_t MOD>
__device__ uint32_t pow1740(uint32_t base) {
    uint32_t b = base % MOD, r = 1u, e = LAM;
    while (e) {                               // products < MOD^2 < 2^24
        if (e & 1u) r = (r * b) % MOD;
        b = (b * b) % MOD;
        e >>= 1u;
    }
    return r;
}
// m = ((r-1)//n * mu) mod n with Python floor semantics; r = c^lam mod n^2.
__device__ uint32_t m_from_r(uint32_t r) {
    if (r == 0u) return Nn - MU;              // x = -1 -> (-mu) mod n = 2480
    uint32_t x = (r - 1u) / Nn;               // exact floor, x < n
    return (x * MU) % Nn;                     // < 3599*1119 < 2^22
}
// Tp[ip]: bits0-5 g_p, bits8-13 m_p, bits16-27 dq_val (m when q|c), bit31 p|ip
__device__ uint32_t tp_entry(uint32_t i) {
    uint32_t a = pow1740<P2>(i);              // c^lam mod p^2 (0 iff p|i)
    uint32_t flag = (i % PP == 0u) ? 0x80000000u : 0u;
    uint32_t gp = 0u, mp = 0u;
    if (!flag) {                              // a ≡ 1 mod p; s = (a-1)/p
        uint32_t s = (a - 1u) / PP;
        mp = (s * CPP) % PP;                  // m mod p
        gp = (mp * GAM) % QQ;
    }
    // dq_val: m given q|c (b=0): r ≡ a (p^2), ≡ 0 (q^2), Garner with b=0
    uint32_t t = (uint32_t)(((uint64_t)((Q2 - a % Q2) % Q2) * IQP) % Q2);
    uint32_t r = a + P2 * t;                  // < n^2, exact
    uint32_t dq = m_from_r(r);                // flag case: a=0 -> r=0 -> 2480
    return gp | (mp << 8) | (dq << 16) | flag;
}
// Tq[iq]: bits0-5 g_q, bits16-27 dp_val (m when p|c), bit31 q|iq
__device__ uint32_t tq_entry(uint32_t i) {
    uint32_t b = pow1740<Q2>(i);              // c^lam mod q^2 (0 iff q|i)
    uint32_t flag = (i % QQ == 0u) ? 0x80000000u : 0u;
    uint32_t gq = 0u;
    if (!flag) {
        uint32_t s = (b - 1u) / QQ;
        uint32_t mq = (s * CQQ) % QQ;         // m mod q
        gq = (mq * GAM) % QQ;
    }
    // dp_val: m given p|c (a=0): r ≡ 0 (p^2), ≡ b (q^2)
    uint32_t t = (uint32_t)(((uint64_t)b * IQP) % Q2);
    uint32_t r = P2 * t;                      // < n^2, exact
    uint32_t dp = m_from_r(r);                // flag case: b=0 -> r=0 -> 2480
    return gq | (dp << 16) | flag;
}

__global__ void build_tables(uint32_t* __restrict__ T) {
    int i = blockIdx.x * blockDim.x + threadIdx.x;
    if (i < TPN) T[i]       = (i < (int)P2) ? tp_entry((uint32_t)i) : 0u;
    if (i < TQN) T[TPN + i] = (i < (int)Q2) ? tq_entry((uint32_t)i) : 0u;
}

// ---- per-element decrypt: ~27 VALU ops + 2 LDS gathers, exact for ALL c ----
__device__ __forceinline__ float dec1(uint32_t c, const uint32_t* sTp,
                                      const uint32_t* sTq, float scale) {
    uint32_t up = sTp[mod24<P2>(c)];
    uint32_t uq = sTq[mod24<Q2>(c)];
    uint32_t gp  = up & 63u;
    uint32_t mp  = (up >> 8) & 63u;
    uint32_t dqv = (up >> 16) & 0xFFFu;
    uint32_t gq  = uq & 63u;
    uint32_t dpv = (uq >> 16) & 0xFFFu;
    uint32_t d = gq + QQ - gp;                // (m_q - m_p)*p^-1 mod q, premult
    d = min(d, d - QQ);
    uint32_t m = mad24_59(d, mp);             // CRT: m_p + 59*d ∈ [0, 3599)
    m = ((int32_t)uq < 0) ? dqv : m;          // q|c: table value from ip
    m = ((int32_t)up < 0) ? dpv : m;          // p|c: table value from iq (2480 if both)
    return fmaxf((float)m * scale, 0.0f);     // relu(m * (inv_scale/1000))
}

__device__ __forceinline__ float4 dec4(uint4 a, const uint32_t* sTp,
                                       const uint32_t* sTq, float scale) {
    float4 o;
    o.x = dec1(a.x, sTp, sTq, scale);
    o.y = dec1(a.y, sTp, sTq, scale);
    o.z = dec1(a.z, sTp, sTq, scale);
    o.w = dec1(a.w, sTp, sTq, scale);
    return o;
}

// Nontemporal float4 store: output is streaming, never re-read by this kernel.
// Keeps the 134 MB write stream from evicting the L3-resident input.
typedef float f32x4_t __attribute__((ext_vector_type(4)));
__device__ __forceinline__ void st4(float4* __restrict__ out, int i, float4 o) {
    f32x4_t v = {o.x, o.y, o.z, o.w};
    __builtin_nontemporal_store(v, reinterpret_cast<f32x4_t*>(out + i));
}

#define BLK 512

// 4-deep software-pipelined body.  Previous version had VGPR_Count=20: a
// register-minimal loop with ONE load in flight and a vmcnt(0) per iteration
// -> latency convoy at 2.4 TB/s (30% HBM), VALUBusy 28%.  Here each round
// issues 4 uint4 loads for round k+1 BEFORE computing/storing round k, so
// steady-state MLP is 4-8 loads/wave and vmcnt waits are progressive (7,6,5,4),
// never 0.  Loads are issued before stores so (FIFO vmcnt) store completion
// never gates compute.  ~55 VGPR: still inside the 64-reg budget for 8 w/SIMD.
__device__ __forceinline__ void dec_loop(const uint4* __restrict__ in4,
                                         float4* __restrict__ out,
                                         const uint32_t* sTp, const uint32_t* sTq,
                                         float scale, int n4) {
    const int stride = gridDim.x * BLK;
    int i = blockIdx.x * BLK + threadIdx.x;
    if (i + 3 * stride < n4) {
        uint4 a0 = in4[i];
        uint4 a1 = in4[i + stride];
        uint4 a2 = in4[i + 2 * stride];
        uint4 a3 = in4[i + 3 * stride];
        int j = i + 4 * stride;
        while (j + 3 * stride < n4) {
            uint4 b0 = in4[j];
            uint4 b1 = in4[j + stride];
            uint4 b2 = in4[j + 2 * stride];
            uint4 b3 = in4[j + 3 * stride];
            st4(out, i,              dec4(a0, sTp, sTq, scale));
            st4(out, i + stride,     dec4(a1, sTp, sTq, scale));
            st4(out, i + 2 * stride, dec4(a2, sTp, sTq, scale));
            st4(out, i + 3 * stride, dec4(a3, sTp, sTq, scale));
            a0 = b0; a1 = b1; a2 = b2; a3 = b3;
            i = j; j += 4 * stride;
        }
        st4(out, i,              dec4(a0, sTp, sTq, scale));
        st4(out, i + stride,     dec4(a1, sTp, sTq, scale));
        st4(out, i + 2 * stride, dec4(a2, sTp, sTq, scale));
        st4(out, i + 3 * stride, dec4(a3, sTp, sTq, scale));
        i += 4 * stride;
    }
    for (; i < n4; i += stride) {             // generic tail (unused at 8192x4096)
        st4(out, i, dec4(in4[i], sTp, sTq, scale));
    }
}

// 1024 blocks x 512 thr: 4 blocks/CU co-resident (28.8KB LDS, 32 waves/CU),
// 16 exact uint4 iterations/thread (4 rounds of 4), no tail.
__global__ __launch_bounds__(BLK, 8) void paillier_main(
        const uint4* __restrict__ in4, float4* __restrict__ out,
        const uint32_t* __restrict__ T, const float* __restrict__ inv_scale,
        int n4) {
    __shared__ uint32_t sT[TT];
    for (int k = threadIdx.x; k < TT / 4; k += BLK)
        ((uint4*)sT)[k] = ((const uint4*)T)[k];
    __syncthreads();
    const uint32_t* sTp = sT;
    const uint32_t* sTq = sT + TPN;

    float scale = inv_scale[0] / 1000.0f;     // matches reference fp32 op order
    dec_loop(in4, out, sTp, sTq, scale, n4);
}

// Fallback (ws too small): build packed tables in-block, same dec path.
__global__ __launch_bounds__(BLK) void paillier_main_fb(
        const uint4* __restrict__ in4, float4* __restrict__ out,
        const float* __restrict__ inv_scale, int n4) {
    __shared__ uint32_t sT[TT];
    for (int i = threadIdx.x; i < (int)P2; i += BLK) sT[i]       = tp_entry((uint32_t)i);
    for (int i = threadIdx.x; i < (int)Q2; i += BLK) sT[TPN + i] = tq_entry((uint32_t)i);
    __syncthreads();
    const uint32_t* sTp = sT;
    const uint32_t* sTq = sT + TPN;
    float scale = inv_scale[0] / 1000.0f;
    dec_loop(in4, out, sTp, sTq, scale, n4);
}

extern "C" void kernel_launch(void* const* d_in, const int* in_sizes, int n_in,
                              void* d_out, int out_size, void* d_ws, size_t ws_size,
                              hipStream_t stream) {
    const uint4* c        = (const uint4*)d_in[0];     // int32 data, read as uint4
    const float* invscale = (const float*)d_in[1];
    float4* out           = (float4*)d_out;

    int n  = in_sizes[0];                              // 33,554,432
    int n4 = n / 4;

    int nblk = 1024;                                   // 4 blocks/CU, all resident
    int need = (n4 + BLK - 1) / BLK;
    if (nblk > need) nblk = need;

    if (ws_size >= WS_NEED && d_ws != nullptr) {
        uint32_t* T = (uint32_t*)d_ws;
        build_tables<<<(TQN + 255) / 256, 256, 0, stream>>>(T);
        paillier_main<<<nblk, BLK, 0, stream>>>(c, out, T, invscale, n4);
    } else {
        paillier_main_fb<<<nblk, BLK, 0, stream>>>(c, out, invscale, n4);
    }
}